// Round 1
// baseline (1070.756 us; speedup 1.0000x reference)
//
#include <hip/hip_runtime.h>
#include <hip/hip_bf16.h>
#include <math.h>

// ---------------------------------------------------------------------------
// AASIST-like net. N = B*S = 4*1024 = 4096 graph nodes.
// Attention trick: e_ij = leaky_relu(s1_i + s2_j + ab).  Sorting j by s2 makes
// the lr branch a threshold; softmax@h becomes prefix/suffix scans (exact).
// ---------------------------------------------------------------------------

#define NN 4096          // graph nodes
#define BB 4             // batch
#define TT0 4096         // time length at conv_time

// ---------------- conv_time: Conv1d(1,128,3,p=1)+BN+ReLU --------------------
__global__ void k_conv_time(const float* __restrict__ x, const float* __restrict__ w,
                            const float* __restrict__ cb, const float* __restrict__ g,
                            const float* __restrict__ bbp, const float* __restrict__ m,
                            const float* __restrict__ v, float* __restrict__ out) {
  int idx = blockIdx.x * 256 + threadIdx.x;     // 4*128*4096
  int t = idx & 4095;
  int o = (idx >> 12) & 127;
  int b = idx >> 19;
  float sc = g[o] * rsqrtf(v[o] + 1e-5f);
  float sh = (cb[o] - m[o]) * sc + bbp[o];
  const float* xb = x + b * 4096;
  float xm = (t > 0) ? xb[t - 1] : 0.f;
  float xc = xb[t];
  float xp = (t < 4095) ? xb[t + 1] : 0.f;
  const float* wo = w + o * 3;
  float y = wo[0] * xm + wo[1] * xc + wo[2] * xp;
  y = y * sc + sh;
  out[idx] = fmaxf(y, 0.f);
}

// ---------- Conv1d(C,O,3,p=1)+BN+ReLU+MaxPool2 (fused), tiled in LDS --------
// block: 64 out-channels x TPT pooled positions; 256 threads.
template <int C, int TIN, int TPT>
__global__ void k_conv_pool(const float* __restrict__ in, const float* __restrict__ w,
                            const float* __restrict__ cb, const float* __restrict__ g,
                            const float* __restrict__ bbp, const float* __restrict__ m,
                            const float* __restrict__ v, float* __restrict__ out, int OCH) {
  constexpr int TOUT = TIN / 2;
  constexpr int W = 2 * TPT + 2;        // staged input window (with halo)
  constexpr int TPTH = TPT / 16;        // pooled outputs per thread
  __shared__ float lds[C * W];

  int bx = blockIdx.x;
  int nTb = TOUT / TPT;
  int tb = bx % nTb;
  int oc = (bx / nTb) % (OCH / 64);
  int b  = bx / (nTb * (OCH / 64));
  int tid = threadIdx.x;

  int t_start = tb * TPT * 2 - 1;       // global input index of lds[.][0]
  for (int e = tid; e < C * W; e += 256) {
    int c = e / W, tl = e % W;
    int t = t_start + tl;
    lds[e] = (t >= 0 && t < TIN) ? in[((size_t)(b * C) + c) * TIN + t] : 0.f;
  }
  __syncthreads();

  int tg = tid & 15, og = tid >> 4;     // 16 tp-groups x 16 o-groups
  int tp0 = tg * TPTH;
  int o0 = oc * 64 + og * 4;

  float acc[4][2 * TPTH];
  #pragma unroll
  for (int i = 0; i < 4; i++)
    #pragma unroll
    for (int p = 0; p < 2 * TPTH; p++) acc[i][p] = 0.f;

  for (int c = 0; c < C; ++c) {
    const float* wrow = w + ((size_t)o0 * C + c) * 3;
    float wv[4][3];
    #pragma unroll
    for (int oi = 0; oi < 4; oi++) {
      wv[oi][0] = wrow[(size_t)oi * C * 3 + 0];
      wv[oi][1] = wrow[(size_t)oi * C * 3 + 1];
      wv[oi][2] = wrow[(size_t)oi * C * 3 + 2];
    }
    float xv[2 * TPTH + 2];
    #pragma unroll
    for (int u = 0; u < 2 * TPTH + 2; ++u) xv[u] = lds[c * W + tp0 * 2 + u];
    #pragma unroll
    for (int oi = 0; oi < 4; oi++)
      #pragma unroll
      for (int p = 0; p < 2 * TPTH; p++)
        acc[oi][p] += wv[oi][0] * xv[p] + wv[oi][1] * xv[p + 1] + wv[oi][2] * xv[p + 2];
  }

  #pragma unroll
  for (int oi = 0; oi < 4; oi++) {
    int o = o0 + oi;
    float sc = g[o] * rsqrtf(v[o] + 1e-5f);
    float sh = (cb[o] - m[o]) * sc + bbp[o];
    #pragma unroll
    for (int tpi = 0; tpi < TPTH; tpi++) {
      float y0 = fmaxf(acc[oi][2 * tpi] * sc + sh, 0.f);
      float y1 = fmaxf(acc[oi][2 * tpi + 1] * sc + sh, 0.f);
      int tp = tb * TPT + tp0 + tpi;
      out[((size_t)(b * OCH) + o) * TOUT + tp] = fmaxf(y0, y1);
    }
  }
}

// --------------------- f32 GEMM: C = A(M,K) @ Wt(N,K)^T + bias --------------
// CHW=true: A is read from [B][K][1024] layout (i = b*1024 + s).
template <int K, bool CHW>
__global__ void k_gemm(const float* __restrict__ A, const float* __restrict__ Wt,
                       const float* __restrict__ bias, float* __restrict__ Cout,
                       int M, int N) {
  __shared__ float As[32][68];
  __shared__ float Bs[32][68];
  int i0 = blockIdx.x * 64, j0 = blockIdx.y * 64;
  int tid = threadIdx.x;
  int tx = tid & 15, ty = tid >> 4;
  float acc[4][4] = {};

  for (int kt = 0; kt < K; kt += 32) {
    if (CHW) {
      int b = i0 >> 10, s0 = i0 & 1023;
      const float* Ab = A + (size_t)b * K * 1024 + (size_t)kt * 1024 + s0;
      for (int e = tid; e < 2048; e += 256) {
        int k = e >> 6, i = e & 63;
        As[k][i] = Ab[(size_t)k * 1024 + i];
      }
    } else {
      for (int e = tid; e < 2048; e += 256) {
        int i = e >> 5, k = e & 31;
        As[k][i] = A[(size_t)(i0 + i) * K + kt + k];
      }
    }
    for (int e = tid; e < 2048; e += 256) {
      int j = e >> 5, k = e & 31;
      Bs[k][j] = Wt[(size_t)(j0 + j) * K + kt + k];
    }
    __syncthreads();
    #pragma unroll 8
    for (int kk = 0; kk < 32; ++kk) {
      float a[4], bv[4];
      #pragma unroll
      for (int u = 0; u < 4; u++) a[u] = As[kk][ty * 4 + u];
      #pragma unroll
      for (int u = 0; u < 4; u++) bv[u] = Bs[kk][tx * 4 + u];
      #pragma unroll
      for (int ii = 0; ii < 4; ii++)
        #pragma unroll
        for (int jj = 0; jj < 4; jj++) acc[ii][jj] += a[ii] * bv[jj];
    }
    __syncthreads();
  }
  #pragma unroll
  for (int ii = 0; ii < 4; ii++) {
    int i = i0 + ty * 4 + ii;
    #pragma unroll
    for (int jj = 0; jj < 4; jj++) {
      int j = j0 + tx * 4 + jj;
      Cout[(size_t)i * N + j] = acc[ii][jj] + bias[j];
    }
  }
}

// ---------------- s1/s2 row dots: s1=h·aw[:D], s2=h·aw[D:] ------------------
template <int D>
__global__ void k_rowdot(const float* __restrict__ h, const float* __restrict__ aw,
                         float* __restrict__ s1, float* __restrict__ s2) {
  int wid = threadIdx.x >> 6, lane = threadIdx.x & 63;
  int i = blockIdx.x * 4 + wid;
  const float* hr = h + (size_t)i * D;
  float d1 = 0.f, d2 = 0.f;
  #pragma unroll
  for (int d = lane; d < D; d += 64) {
    float hv = hr[d];
    d1 += hv * aw[d];
    d2 += hv * aw[D + d];
  }
  for (int off = 32; off; off >>= 1) {
    d1 += __shfl_down(d1, off, 64);
    d2 += __shfl_down(d2, off, 64);
  }
  if (lane == 0) { s1[i] = d1; s2[i] = d2; }
}

// ---------------- max over s2 ------------------------------------------------
__global__ void k_max4096(const float* __restrict__ s2v, float* __restrict__ M2out) {
  __shared__ float wred[4];
  float mv = -3.4e38f;
  for (int r = threadIdx.x; r < NN; r += 256) mv = fmaxf(mv, s2v[r]);
  for (int off = 32; off; off >>= 1) mv = fmaxf(mv, __shfl_down(mv, off, 64));
  int lane = threadIdx.x & 63, wv = threadIdx.x >> 6;
  if (lane == 0) wred[wv] = mv;
  __syncthreads();
  if (threadIdx.x == 0)
    M2out[0] = fmaxf(fmaxf(wred[0], wred[1]), fmaxf(wred[2], wred[3]));
}

// ---------------- bitonic sort (value,index) of 4096 ------------------------
__global__ void k_sort4096(const float* __restrict__ s2v, float* __restrict__ svals,
                           int* __restrict__ sidx) {
  __shared__ float v[NN];
  __shared__ int id[NN];
  for (int e = threadIdx.x; e < NN; e += 256) { v[e] = s2v[e]; id[e] = e; }
  __syncthreads();
  for (int k = 2; k <= NN; k <<= 1) {
    for (int j = k >> 1; j > 0; j >>= 1) {
      for (int e = threadIdx.x; e < NN; e += 256) {
        int p = e ^ j;
        if (p > e) {
          bool up = ((e & k) == 0);
          float a = v[e], b2 = v[p];
          if (up ? (a > b2) : (a < b2)) {
            v[e] = b2; v[p] = a;
            int t = id[e]; id[e] = id[p]; id[p] = t;
          }
        }
      }
      __syncthreads();
    }
  }
  for (int e = threadIdx.x; e < NN; e += 256) { svals[e] = v[e]; sidx[e] = id[e]; }
}

// ------------- per-row threshold + A/B factors ------------------------------
__global__ void k_tvals(const float* __restrict__ s1, const float* __restrict__ svals,
                        const float* __restrict__ M2p, const float* __restrict__ abp,
                        int* __restrict__ tarr, float* __restrict__ Aarr,
                        float* __restrict__ Barr) {
  int i = blockIdx.x * 256 + threadIdx.x;
  float ab = abp[0], M2 = M2p[0];
  float alpha = s1[i] + ab;
  float cthr = -alpha;                        // j in S+ iff s2_j >= cthr
  int lo = 0, hi = NN;
  while (lo < hi) {
    int mid = (lo + hi) >> 1;
    if (svals[mid] < cthr) lo = mid + 1; else hi = mid;
  }
  tarr[i] = lo;
  float e1 = alpha + M2;
  float gam = fmaxf(e1, 0.01f * e1);          // = leaky_relu(e1) = row max of lr(x)
  Aarr[i] = expf(e1 - gam);
  Barr[i] = expf(0.01f * e1 - gam);
}

// ------------- sorted-order exp weights -------------------------------------
__global__ void k_weights(const float* __restrict__ svals, const float* __restrict__ M2p,
                          float* __restrict__ wp, float* __restrict__ wm) {
  int r = blockIdx.x * 256 + threadIdx.x;
  float M2 = M2p[0];
  float d = svals[r] - M2;                    // <= 0
  wp[r] = expf(d);
  wm[r] = expf(0.01f * d);
}

// ------------- scalar denominator scans (one block) -------------------------
__global__ void k_scan_den(const float* __restrict__ wp, const float* __restrict__ wm,
                           float* __restrict__ preden, float* __restrict__ sufden) {
  __shared__ float csP[256], csM[256];
  int tid = threadIdx.x;
  int base = tid * 16;
  float sm = 0.f, sp = 0.f;
  for (int u = 0; u < 16; u++) { sm += wm[base + u]; sp += wp[base + u]; }
  csM[tid] = sm; csP[tid] = sp;
  __syncthreads();
  float offM = 0.f;
  for (int c = 0; c < tid; c++) offM += csM[c];
  float offP = 0.f;
  for (int c = tid + 1; c < 256; c++) offP += csP[c];
  float run = offM;
  for (int u = 0; u < 16; u++) { preden[base + u] = run; run += wm[base + u]; }
  if (tid == 255) preden[NN] = run;
  float runp = offP;
  if (tid == 255) sufden[NN] = 0.f;
  for (int u = 15; u >= 0; u--) { runp += wp[base + u]; sufden[base + u] = runp; }
}

// ------------- chunk column sums (128 chunks of 32 sorted rows) -------------
template <int D>
__global__ void k_chunksum(const float* __restrict__ h, const int* __restrict__ sidx,
                           const float* __restrict__ wp, const float* __restrict__ wm,
                           float* __restrict__ csP, float* __restrict__ csM) {
  constexpr int CPT = D / 256;
  int c = blockIdx.x, tid = threadIdx.x;
  __shared__ int lidx[32];
  __shared__ float lwp[32], lwm[32];
  if (tid < 32) {
    int r = c * 32 + tid;
    lidx[tid] = sidx[r]; lwp[tid] = wp[r]; lwm[tid] = wm[r];
  }
  __syncthreads();
  float aP[CPT], aM[CPT];
  #pragma unroll
  for (int q = 0; q < CPT; q++) { aP[q] = 0.f; aM[q] = 0.f; }
  for (int u = 0; u < 32; u++) {
    const float* hr = h + (size_t)lidx[u] * D;
    float fp = lwp[u], fm = lwm[u];
    #pragma unroll
    for (int q = 0; q < CPT; q++) {
      float hv = hr[tid + q * 256];
      aP[q] += fp * hv; aM[q] += fm * hv;
    }
  }
  #pragma unroll
  for (int q = 0; q < CPT; q++) {
    csP[(size_t)c * D + tid + q * 256] = aP[q];
    csM[(size_t)c * D + tid + q * 256] = aM[q];
  }
}

// ------------- chunk offsets (one block, sequential over 128 chunks) --------
template <int D>
__global__ void k_chunkoff(const float* __restrict__ csP, const float* __restrict__ csM,
                           float* __restrict__ offP, float* __restrict__ offM) {
  #pragma unroll
  for (int q = 0; q < D / 256; q++) {
    int d = threadIdx.x + q * 256;
    float rm = 0.f;
    for (int c = 0; c < 128; c++) { offM[(size_t)c * D + d] = rm; rm += csM[(size_t)c * D + d]; }
    float rp = 0.f;
    for (int c = 127; c >= 0; c--) { offP[(size_t)c * D + d] = rp; rp += csP[(size_t)c * D + d]; }
  }
}

// ------------- write full prefix (Pre) and suffix (Suf) arrays --------------
template <int D>
__global__ void k_scanwrite(const float* __restrict__ h, const int* __restrict__ sidx,
                            const float* __restrict__ wp, const float* __restrict__ wm,
                            const float* __restrict__ offP, const float* __restrict__ offM,
                            float* __restrict__ Pre, float* __restrict__ Suf) {
  constexpr int CPT = D / 256;
  int c = blockIdx.x, tid = threadIdx.x;
  __shared__ int lidx[32];
  __shared__ float lwp[32], lwm[32];
  if (tid < 32) {
    int r = c * 32 + tid;
    lidx[tid] = sidx[r]; lwp[tid] = wp[r]; lwm[tid] = wm[r];
  }
  __syncthreads();
  float runM[CPT], runP[CPT];
  #pragma unroll
  for (int q = 0; q < CPT; q++) {
    int d = tid + q * 256;
    runM[q] = offM[(size_t)c * D + d];
    runP[q] = offP[(size_t)c * D + d];
  }
  // prefix: Pre[t] = sum_{r<t} wm_r h_r ; write rows c*32 .. c*32+31 (+ row NN by last chunk)
  for (int u = 0; u < 32; u++) {
    const float* hr = h + (size_t)lidx[u] * D;
    float fm = lwm[u];
    #pragma unroll
    for (int q = 0; q < CPT; q++) {
      int d = tid + q * 256;
      Pre[(size_t)(c * 32 + u) * D + d] = runM[q];
      runM[q] += fm * hr[d];
    }
  }
  if (c == 127) {
    #pragma unroll
    for (int q = 0; q < CPT; q++) Pre[(size_t)NN * D + tid + q * 256] = runM[q];
  }
  // suffix: Suf[t] = sum_{r>=t} wp_r h_r ; write rows c*32+31 .. c*32 (+ row NN zero)
  if (c == 127) {
    #pragma unroll
    for (int q = 0; q < CPT; q++) Suf[(size_t)NN * D + tid + q * 256] = 0.f;
  }
  for (int u = 31; u >= 0; u--) {
    const float* hr = h + (size_t)lidx[u] * D;
    float fp = lwp[u];
    #pragma unroll
    for (int q = 0; q < CPT; q++) {
      int d = tid + q * 256;
      runP[q] += fp * hr[d];
      Suf[(size_t)(c * 32 + u) * D + d] = runP[q];
    }
  }
}

// ------------- apply: out_i = (A*Suf[t] + B*Pre[t]) / (A*sufden + B*preden) -
template <int D>
__global__ void k_apply(const float* __restrict__ Pre, const float* __restrict__ Suf,
                        const float* __restrict__ preden, const float* __restrict__ sufden,
                        const int* __restrict__ tarr, const float* __restrict__ Aarr,
                        const float* __restrict__ Barr, float* __restrict__ outg) {
  int i = blockIdx.x;
  int t = tarr[i];
  float A = Aarr[i], Bv = Barr[i];
  float den = A * sufden[t] + Bv * preden[t];
  float inv = 1.f / den;
  const float* Pr = Pre + (size_t)t * D;
  const float* Sr = Suf + (size_t)t * D;
  for (int d = threadIdx.x; d < D; d += 256)
    outg[(size_t)i * D + d] = (A * Sr[d] + Bv * Pr[d]) * inv;
}

// ------------- mean-pool over S + final Linear(256,2) -----------------------
__global__ void k_head(const float* __restrict__ g2, const float* __restrict__ fcw,
                       const float* __restrict__ fcb, float* __restrict__ out) {
  __shared__ float pooled[256];
  int b = blockIdx.x, c = threadIdx.x;
  const float* base = g2 + (size_t)b * 1024 * 256 + c;
  float s = 0.f;
  for (int r = 0; r < 1024; r++) s += base[(size_t)r * 256];
  pooled[c] = s * (1.f / 1024.f);
  __syncthreads();
  if (c < 2) {
    float acc = fcb[c];
    for (int cc = 0; cc < 256; cc++) acc += pooled[cc] * fcw[c * 256 + cc];
    out[b * 2 + c] = acc;
  }
}

// ---------------------------------------------------------------------------
extern "C" void kernel_launch(void* const* d_in, const int* in_sizes, int n_in,
                              void* d_out, int out_size, void* d_ws, size_t ws_size,
                              hipStream_t stream) {
  const float* x    = (const float*)d_in[0];
  const float* ctw  = (const float*)d_in[1];
  const float* ctb  = (const float*)d_in[2];
  const float* bn0g = (const float*)d_in[3];
  const float* bn0b = (const float*)d_in[4];
  const float* bn0m = (const float*)d_in[5];
  const float* bn0v = (const float*)d_in[6];
  const float* c1w  = (const float*)d_in[7];
  const float* c1b  = (const float*)d_in[8];
  const float* bn1g = (const float*)d_in[9];
  const float* bn1b = (const float*)d_in[10];
  const float* bn1m = (const float*)d_in[11];
  const float* bn1v = (const float*)d_in[12];
  const float* c2w  = (const float*)d_in[13];
  const float* c2b  = (const float*)d_in[14];
  const float* bn2g = (const float*)d_in[15];
  const float* bn2b = (const float*)d_in[16];
  const float* bn2m = (const float*)d_in[17];
  const float* bn2v = (const float*)d_in[18];
  const float* g1w  = (const float*)d_in[19];
  const float* g1b  = (const float*)d_in[20];
  const float* g1aw = (const float*)d_in[21];
  const float* g1ab = (const float*)d_in[22];
  const float* g2w  = (const float*)d_in[23];
  const float* g2b  = (const float*)d_in[24];
  const float* g2aw = (const float*)d_in[25];
  const float* g2ab = (const float*)d_in[26];
  const float* fcw  = (const float*)d_in[27];
  const float* fcb  = (const float*)d_in[28];
  float* ws = (float*)d_ws;

  const size_t SLOT = (size_t)(NN + 1) * 512;   // 2,097,664 floats
  float* slot0 = ws;                 // buf0 -> Suf
  float* slot1 = ws + SLOT;          // buf1 -> Pre
  float* slot2 = ws + 2 * SLOT;      // buf2 -> g1 -> g2
  float* slot3 = ws + 3 * SLOT;      // h1 -> h2
  float* sm    = ws + 4 * SLOT;      // smalls
  float* s1    = sm;           // 4096
  float* s2    = sm + 4096;
  float* svals = sm + 8192;
  int*   sidx  = (int*)(sm + 12288);
  int*   tarr  = (int*)(sm + 16384);
  float* Aarr  = sm + 20480;
  float* Barr  = sm + 24576;
  float* wp    = sm + 28672;
  float* wm    = sm + 32768;
  float* preden = sm + 36864;        // 4097
  float* sufden = sm + 40968;        // 4097
  float* csP   = sm + 45072;         // 128*512
  float* csM   = csP + 65536;
  float* offP  = csM + 65536;
  float* offM  = offP + 65536;
  float* M2p   = offM + 65536;

  // ---- convs ----
  k_conv_time<<<BB * 128 * TT0 / 256, 256, 0, stream>>>(x, ctw, ctb, bn0g, bn0b, bn0m, bn0v, slot0);
  k_conv_pool<128, 4096, 32><<<BB * (2048 / 32) * (256 / 64), 256, 0, stream>>>(
      slot0, c1w, c1b, bn1g, bn1b, bn1m, bn1v, slot1, 256);
  k_conv_pool<256, 2048, 16><<<BB * (1024 / 16) * (512 / 64), 256, 0, stream>>>(
      slot1, c2w, c2b, bn2g, bn2b, bn2m, bn2v, slot2, 512);

  // ---- GAT1: fc (reads CHW buf2 transposed) ----
  k_gemm<512, true><<<dim3(64, 8), 256, 0, stream>>>(slot2, g1w, g1b, slot3, NN, 512);
  k_rowdot<512><<<NN / 4, 256, 0, stream>>>(slot3, g1aw, s1, s2);
  k_max4096<<<1, 256, 0, stream>>>(s2, M2p);
  k_sort4096<<<1, 256, 0, stream>>>(s2, svals, sidx);
  k_tvals<<<NN / 256, 256, 0, stream>>>(s1, svals, M2p, g1ab, tarr, Aarr, Barr);
  k_weights<<<NN / 256, 256, 0, stream>>>(svals, M2p, wp, wm);
  k_scan_den<<<1, 256, 0, stream>>>(wp, wm, preden, sufden);
  k_chunksum<512><<<128, 256, 0, stream>>>(slot3, sidx, wp, wm, csP, csM);
  k_chunkoff<512><<<1, 256, 0, stream>>>(csP, csM, offP, offM);
  k_scanwrite<512><<<128, 256, 0, stream>>>(slot3, sidx, wp, wm, offP, offM, slot1, slot0);
  k_apply<512><<<NN, 256, 0, stream>>>(slot1, slot0, preden, sufden, tarr, Aarr, Barr, slot2);

  // ---- GAT2: fc (row-major g1) ----
  k_gemm<512, false><<<dim3(64, 4), 256, 0, stream>>>(slot2, g2w, g2b, slot3, NN, 256);
  k_rowdot<256><<<NN / 4, 256, 0, stream>>>(slot3, g2aw, s1, s2);
  k_max4096<<<1, 256, 0, stream>>>(s2, M2p);
  k_sort4096<<<1, 256, 0, stream>>>(s2, svals, sidx);
  k_tvals<<<NN / 256, 256, 0, stream>>>(s1, svals, M2p, g2ab, tarr, Aarr, Barr);
  k_weights<<<NN / 256, 256, 0, stream>>>(svals, M2p, wp, wm);
  k_scan_den<<<1, 256, 0, stream>>>(wp, wm, preden, sufden);
  k_chunksum<256><<<128, 256, 0, stream>>>(slot3, sidx, wp, wm, csP, csM);
  k_chunkoff<256><<<1, 256, 0, stream>>>(csP, csM, offP, offM);
  k_scanwrite<256><<<128, 256, 0, stream>>>(slot3, sidx, wp, wm, offP, offM, slot1, slot0);
  k_apply<256><<<NN, 256, 0, stream>>>(slot1, slot0, preden, sufden, tarr, Aarr, Barr, slot2);

  // ---- head ----
  k_head<<<BB, 256, 0, stream>>>(slot2, fcw, fcb, (float*)d_out);
}

// Round 2
// 566.293 us; speedup vs baseline: 1.8908x; 1.8908x over previous
//
#include <hip/hip_runtime.h>
#include <hip/hip_bf16.h>
#include <math.h>

// ---------------------------------------------------------------------------
// AASIST-like net. N = B*S = 4*1024 = 4096 graph nodes.
// Attention trick: e_ij = leaky_relu(s1_i + s2_j + ab).  Sorting j by s2 makes
// the lr branch a threshold; softmax@h becomes prefix/suffix scans (exact).
// ---------------------------------------------------------------------------

#define NN 4096          // graph nodes
#define BB 4             // batch
#define TT0 4096         // time length at conv_time

// ---------------- conv_time: Conv1d(1,128,3,p=1)+BN+ReLU --------------------
__global__ void k_conv_time(const float* __restrict__ x, const float* __restrict__ w,
                            const float* __restrict__ cb, const float* __restrict__ g,
                            const float* __restrict__ bbp, const float* __restrict__ m,
                            const float* __restrict__ v, float* __restrict__ out) {
  int idx = blockIdx.x * 256 + threadIdx.x;     // 4*128*4096
  int t = idx & 4095;
  int o = (idx >> 12) & 127;
  int b = idx >> 19;
  float sc = g[o] * rsqrtf(v[o] + 1e-5f);
  float sh = (cb[o] - m[o]) * sc + bbp[o];
  const float* xb = x + b * 4096;
  float xm = (t > 0) ? xb[t - 1] : 0.f;
  float xc = xb[t];
  float xp = (t < 4095) ? xb[t + 1] : 0.f;
  const float* wo = w + o * 3;
  float y = wo[0] * xm + wo[1] * xc + wo[2] * xp;
  y = y * sc + sh;
  out[idx] = fmaxf(y, 0.f);
}

// ---------- Conv1d(C,O,3,p=1)+BN+ReLU+MaxPool2, x+w staged in LDS -----------
// block: 64 out-channels x 64 pooled positions (128 conv pos); 256 threads.
// thread: 4 oc x 8 conv pos -> per channel 96 FMA vs ~6 LDS vector reads.
template <int C, int TIN>
__global__ void k_conv_pool2(const float* __restrict__ in, const float* __restrict__ w,
                             const float* __restrict__ cb, const float* __restrict__ g,
                             const float* __restrict__ bbp, const float* __restrict__ m,
                             const float* __restrict__ v, float* __restrict__ out, int OCH) {
  constexpr int TOUT = TIN / 2;
  constexpr int W = 132;            // 128 conv + 2 halo, padded to mult of 4
  constexpr int CC = 32;            // channel chunk
  __shared__ float xs[CC][W];
  __shared__ float wsh[CC][192];    // [cc][oo*3+k], 64 oc

  int bx = blockIdx.x;
  int nT = TOUT / 64;
  int tb = bx % nT;
  int ob = (bx / nT) % (OCH / 64);
  int b  = bx / (nT * (OCH / 64));
  int tid = threadIdx.x;
  int tg = tid & 15, og = tid >> 4;

  float acc[4][8];
  #pragma unroll
  for (int i = 0; i < 4; i++)
    #pragma unroll
    for (int q = 0; q < 8; q++) acc[i][q] = 0.f;

  int t0 = tb * 128;                // first conv position of this block
  const float* wbase = w + (size_t)(ob * 64) * C * 3;

  for (int c0 = 0; c0 < C; c0 += CC) {
    // stage x chunk: xs[cc][tl] = in[c0+cc][t0-1+tl], zeros at edges/pad
    for (int e = tid; e < CC * W; e += 256) {
      int cc = e / W, tl = e - cc * W;
      int t = t0 - 1 + tl;
      float val = 0.f;
      if (tl < 130 && t >= 0 && t < TIN)
        val = in[((size_t)(b * C) + c0 + cc) * TIN + t];
      xs[cc][tl] = val;
    }
    // stage w chunk (coalesced 96-float rows per oc)
    for (int e = tid; e < CC * 192; e += 256) {
      int oo = e / 96, r = e - oo * 96;   // r = cc*3+k
      int cc = r / 3, k = r - cc * 3;
      wsh[cc][oo * 3 + k] = wbase[(size_t)oo * C * 3 + (size_t)c0 * 3 + r];
    }
    __syncthreads();
    #pragma unroll 4
    for (int cc = 0; cc < CC; ++cc) {
      float xv[10];
      #pragma unroll
      for (int u = 0; u < 10; u++) xv[u] = xs[cc][tg * 8 + u];
      float wv[12];
      #pragma unroll
      for (int u = 0; u < 12; u++) wv[u] = wsh[cc][og * 12 + u];
      #pragma unroll
      for (int oi = 0; oi < 4; oi++)
        #pragma unroll
        for (int q = 0; q < 8; q++)
          acc[oi][q] += wv[oi * 3] * xv[q] + wv[oi * 3 + 1] * xv[q + 1]
                      + wv[oi * 3 + 2] * xv[q + 2];
    }
    __syncthreads();
  }

  int tpbase = tb * 64 + tg * 4;
  #pragma unroll
  for (int oi = 0; oi < 4; oi++) {
    int o = ob * 64 + og * 4 + oi;
    float sc = g[o] * rsqrtf(v[o] + 1e-5f);
    float sh = (cb[o] - m[o]) * sc + bbp[o];
    #pragma unroll
    for (int qp = 0; qp < 4; qp++) {
      float y0 = acc[oi][2 * qp] * sc + sh;
      float y1 = acc[oi][2 * qp + 1] * sc + sh;
      out[((size_t)(b * OCH) + o) * TOUT + tpbase + qp] = fmaxf(fmaxf(y0, y1), 0.f);
    }
  }
}

// --------------------- f32 GEMM: C = A(M,K) @ Wt(N,K)^T + bias --------------
// TM x 64 tile, micro (TM/16) x 4. CHW=true: A read from [B][K][1024] layout.
template <int K, bool CHW, int TM>
__global__ void k_gemm(const float* __restrict__ A, const float* __restrict__ Wt,
                       const float* __restrict__ bias, float* __restrict__ Cout,
                       int M, int N) {
  constexpr int MT = TM / 16;
  __shared__ float As[32][TM + 4];
  __shared__ float Bs[32][68];
  int i0 = blockIdx.x * TM, j0 = blockIdx.y * 64;
  int tid = threadIdx.x;
  int tx = tid & 15, ty = tid >> 4;
  float acc[MT][4];
  #pragma unroll
  for (int ii = 0; ii < MT; ii++)
    #pragma unroll
    for (int jj = 0; jj < 4; jj++) acc[ii][jj] = 0.f;

  for (int kt = 0; kt < K; kt += 32) {
    if (CHW) {
      int b = i0 >> 10, s0 = i0 & 1023;
      const float* Ab = A + (size_t)b * K * 1024 + (size_t)kt * 1024 + s0;
      for (int e = tid; e < 32 * TM; e += 256) {
        int k = e / TM, i = e - k * TM;
        As[k][i] = Ab[(size_t)k * 1024 + i];
      }
    } else {
      for (int e = tid; e < 32 * TM; e += 256) {
        int i = e >> 5, k = e & 31;
        As[k][i] = A[(size_t)(i0 + i) * K + kt + k];
      }
    }
    for (int e = tid; e < 2048; e += 256) {
      int j = e >> 5, k = e & 31;
      Bs[k][j] = Wt[(size_t)(j0 + j) * K + kt + k];
    }
    __syncthreads();
    #pragma unroll 8
    for (int kk = 0; kk < 32; ++kk) {
      float a[MT], bv[4];
      #pragma unroll
      for (int u = 0; u < MT; u++) a[u] = As[kk][ty * MT + u];
      #pragma unroll
      for (int u = 0; u < 4; u++) bv[u] = Bs[kk][tx * 4 + u];
      #pragma unroll
      for (int ii = 0; ii < MT; ii++)
        #pragma unroll
        for (int jj = 0; jj < 4; jj++) acc[ii][jj] += a[ii] * bv[jj];
    }
    __syncthreads();
  }
  #pragma unroll
  for (int ii = 0; ii < MT; ii++) {
    int i = i0 + ty * MT + ii;
    #pragma unroll
    for (int jj = 0; jj < 4; jj++) {
      int j = j0 + tx * 4 + jj;
      Cout[(size_t)i * N + j] = acc[ii][jj] + bias[j];
    }
  }
}

// ---------------- s1/s2 row dots: s1=h·aw[:D], s2=h·aw[D:] ------------------
template <int D>
__global__ void k_rowdot(const float* __restrict__ h, const float* __restrict__ aw,
                         float* __restrict__ s1, float* __restrict__ s2) {
  int wid = threadIdx.x >> 6, lane = threadIdx.x & 63;
  int i = blockIdx.x * 4 + wid;
  const float* hr = h + (size_t)i * D;
  float d1 = 0.f, d2 = 0.f;
  #pragma unroll
  for (int d = lane; d < D; d += 64) {
    float hv = hr[d];
    d1 += hv * aw[d];
    d2 += hv * aw[D + d];
  }
  for (int off = 32; off; off >>= 1) {
    d1 += __shfl_down(d1, off, 64);
    d2 += __shfl_down(d2, off, 64);
  }
  if (lane == 0) { s1[i] = d1; s2[i] = d2; }
}

// ---------------- rank by counting (replaces bitonic sort) ------------------
// grid (16,4): blockIdx.x covers j, blockIdx.y covers a 1024-chunk of r.
__global__ void k_rank(const float* __restrict__ s2v, int* __restrict__ rnk) {
  __shared__ float ls[1024];
  int j = blockIdx.x * 256 + threadIdx.x;
  int base = blockIdx.y * 1024;
  float vj = s2v[j];
  for (int e = threadIdx.x; e < 1024; e += 256) ls[e] = s2v[base + e];
  __syncthreads();
  int cnt = 0;
  #pragma unroll 8
  for (int r = 0; r < 1024; ++r) {
    float vr = ls[r];
    cnt += (vr < vj || (vr == vj && (base + r) < j)) ? 1 : 0;
  }
  atomicAdd(&rnk[j], cnt);
}

__global__ void k_scatter(const float* __restrict__ s2v, const int* __restrict__ rnk,
                          float* __restrict__ svals, int* __restrict__ sidx) {
  int j = blockIdx.x * 256 + threadIdx.x;
  int r = rnk[j];
  svals[r] = s2v[j];
  sidx[r] = j;
}

// ------------- per-row threshold + A/B factors + sorted exp weights ---------
__global__ void k_tw(const float* __restrict__ s1, const float* __restrict__ svals,
                     const float* __restrict__ abp, int* __restrict__ tarr,
                     float* __restrict__ Aarr, float* __restrict__ Barr,
                     float* __restrict__ wp, float* __restrict__ wm) {
  int i = blockIdx.x * 256 + threadIdx.x;
  float ab = abp[0], M2 = svals[NN - 1];
  float alpha = s1[i] + ab;
  float cthr = -alpha;                        // j in S+ iff s2_j >= cthr
  int lo = 0, hi = NN;
  while (lo < hi) {
    int mid = (lo + hi) >> 1;
    if (svals[mid] < cthr) lo = mid + 1; else hi = mid;
  }
  tarr[i] = lo;
  float e1 = alpha + M2;
  float gam = fmaxf(e1, 0.01f * e1);          // = leaky_relu(e1) = row max of lr(x)
  Aarr[i] = expf(e1 - gam);
  Barr[i] = expf(0.01f * e1 - gam);
  float d = svals[i] - M2;                    // <= 0
  wp[i] = expf(d);
  wm[i] = expf(0.01f * d);
}

// ------------- scalar denominator scans (one block) -------------------------
__global__ void k_scan_den(const float* __restrict__ wp, const float* __restrict__ wm,
                           float* __restrict__ preden, float* __restrict__ sufden) {
  __shared__ float csP[256], csM[256];
  int tid = threadIdx.x;
  int base = tid * 16;
  float sm = 0.f, sp = 0.f;
  for (int u = 0; u < 16; u++) { sm += wm[base + u]; sp += wp[base + u]; }
  csM[tid] = sm; csP[tid] = sp;
  __syncthreads();
  float offM = 0.f;
  for (int c = 0; c < tid; c++) offM += csM[c];
  float offP = 0.f;
  for (int c = tid + 1; c < 256; c++) offP += csP[c];
  float run = offM;
  for (int u = 0; u < 16; u++) { preden[base + u] = run; run += wm[base + u]; }
  if (tid == 255) preden[NN] = run;
  float runp = offP;
  if (tid == 255) sufden[NN] = 0.f;
  for (int u = 15; u >= 0; u--) { runp += wp[base + u]; sufden[base + u] = runp; }
}

// ------------- chunk column sums (128 chunks of 32 sorted rows) -------------
template <int D>
__global__ void k_chunksum(const float* __restrict__ h, const int* __restrict__ sidx,
                           const float* __restrict__ wp, const float* __restrict__ wm,
                           float* __restrict__ csP, float* __restrict__ csM) {
  constexpr int CPT = D / 256;
  int c = blockIdx.x, tid = threadIdx.x;
  __shared__ int lidx[32];
  __shared__ float lwp[32], lwm[32];
  if (tid < 32) {
    int r = c * 32 + tid;
    lidx[tid] = sidx[r]; lwp[tid] = wp[r]; lwm[tid] = wm[r];
  }
  __syncthreads();
  float aP[CPT], aM[CPT];
  #pragma unroll
  for (int q = 0; q < CPT; q++) { aP[q] = 0.f; aM[q] = 0.f; }
  for (int u = 0; u < 32; u++) {
    const float* hr = h + (size_t)lidx[u] * D;
    float fp = lwp[u], fm = lwm[u];
    #pragma unroll
    for (int q = 0; q < CPT; q++) {
      float hv = hr[tid + q * 256];
      aP[q] += fp * hv; aM[q] += fm * hv;
    }
  }
  #pragma unroll
  for (int q = 0; q < CPT; q++) {
    csP[(size_t)c * D + tid + q * 256] = aP[q];
    csM[(size_t)c * D + tid + q * 256] = aM[q];
  }
}

// ------------- chunk offsets, batched loads (kills latency chain) -----------
template <int D>
__global__ void k_chunkoff(const float* __restrict__ csP, const float* __restrict__ csM,
                           float* __restrict__ offP, float* __restrict__ offM) {
  int d = blockIdx.x * 256 + threadIdx.x;
  float rm = 0.f;
  for (int cb = 0; cb < 128; cb += 16) {
    float vals[16];
    #pragma unroll
    for (int u = 0; u < 16; u++) vals[u] = csM[(size_t)(cb + u) * D + d];
    #pragma unroll
    for (int u = 0; u < 16; u++) { offM[(size_t)(cb + u) * D + d] = rm; rm += vals[u]; }
  }
  float rp = 0.f;
  for (int cb = 127; cb >= 15; cb -= 16) {
    float vals[16];
    #pragma unroll
    for (int u = 0; u < 16; u++) vals[u] = csP[(size_t)(cb - u) * D + d];
    #pragma unroll
    for (int u = 0; u < 16; u++) { offP[(size_t)(cb - u) * D + d] = rp; rp += vals[u]; }
  }
}

// ------------- write full prefix (Pre) and suffix (Suf) arrays --------------
template <int D>
__global__ void k_scanwrite(const float* __restrict__ h, const int* __restrict__ sidx,
                            const float* __restrict__ wp, const float* __restrict__ wm,
                            const float* __restrict__ offP, const float* __restrict__ offM,
                            float* __restrict__ Pre, float* __restrict__ Suf) {
  constexpr int CPT = D / 256;
  int c = blockIdx.x, tid = threadIdx.x;
  __shared__ int lidx[32];
  __shared__ float lwp[32], lwm[32];
  if (tid < 32) {
    int r = c * 32 + tid;
    lidx[tid] = sidx[r]; lwp[tid] = wp[r]; lwm[tid] = wm[r];
  }
  __syncthreads();
  float runM[CPT], runP[CPT];
  #pragma unroll
  for (int q = 0; q < CPT; q++) {
    int d = tid + q * 256;
    runM[q] = offM[(size_t)c * D + d];
    runP[q] = offP[(size_t)c * D + d];
  }
  for (int u = 0; u < 32; u++) {
    const float* hr = h + (size_t)lidx[u] * D;
    float fm = lwm[u];
    #pragma unroll
    for (int q = 0; q < CPT; q++) {
      int d = tid + q * 256;
      Pre[(size_t)(c * 32 + u) * D + d] = runM[q];
      runM[q] += fm * hr[d];
    }
  }
  if (c == 127) {
    #pragma unroll
    for (int q = 0; q < CPT; q++) Pre[(size_t)NN * D + tid + q * 256] = runM[q];
    #pragma unroll
    for (int q = 0; q < CPT; q++) Suf[(size_t)NN * D + tid + q * 256] = 0.f;
  }
  for (int u = 31; u >= 0; u--) {
    const float* hr = h + (size_t)lidx[u] * D;
    float fp = lwp[u];
    #pragma unroll
    for (int q = 0; q < CPT; q++) {
      int d = tid + q * 256;
      runP[q] += fp * hr[d];
      Suf[(size_t)(c * 32 + u) * D + d] = runP[q];
    }
  }
}

// ------------- apply: out_i = (A*Suf[t] + B*Pre[t]) / (A*sufden + B*preden) -
template <int D>
__global__ void k_apply(const float* __restrict__ Pre, const float* __restrict__ Suf,
                        const float* __restrict__ preden, const float* __restrict__ sufden,
                        const int* __restrict__ tarr, const float* __restrict__ Aarr,
                        const float* __restrict__ Barr, float* __restrict__ outg) {
  int i = blockIdx.x;
  int t = tarr[i];
  float A = Aarr[i], Bv = Barr[i];
  float den = A * sufden[t] + Bv * preden[t];
  float inv = 1.f / den;
  const float* Pr = Pre + (size_t)t * D;
  const float* Sr = Suf + (size_t)t * D;
  for (int d = threadIdx.x; d < D; d += 256)
    outg[(size_t)i * D + d] = (A * Sr[d] + Bv * Pr[d]) * inv;
}

// ------------- mean-pool over S (2-stage) + final Linear(256,2) -------------
__global__ void k_pool(const float* __restrict__ g2, float* __restrict__ pp) {
  int b = blockIdx.x >> 4, ch = blockIdx.x & 15;
  const float* base = g2 + ((size_t)(b * 1024) + ch * 64) * 256 + threadIdx.x;
  float s = 0.f;
  for (int r = 0; r < 64; r++) s += base[(size_t)r * 256];
  pp[(size_t)blockIdx.x * 256 + threadIdx.x] = s;
}

__global__ void k_head2(const float* __restrict__ pp, const float* __restrict__ fcw,
                        const float* __restrict__ fcb, float* __restrict__ out) {
  __shared__ float pooled[4][256];
  int tid = threadIdx.x;
  for (int b = 0; b < 4; b++) {
    float s = 0.f;
    for (int ch = 0; ch < 16; ch++) s += pp[(size_t)(b * 16 + ch) * 256 + tid];
    pooled[b][tid] = s * (1.f / 1024.f);
  }
  __syncthreads();
  if (tid < 8) {
    int b = tid >> 1, c = tid & 1;
    float acc = fcb[c];
    for (int cc = 0; cc < 256; cc++) acc += pooled[b][cc] * fcw[c * 256 + cc];
    out[b * 2 + c] = acc;
  }
}

// ---------------------------------------------------------------------------
extern "C" void kernel_launch(void* const* d_in, const int* in_sizes, int n_in,
                              void* d_out, int out_size, void* d_ws, size_t ws_size,
                              hipStream_t stream) {
  const float* x    = (const float*)d_in[0];
  const float* ctw  = (const float*)d_in[1];
  const float* ctb  = (const float*)d_in[2];
  const float* bn0g = (const float*)d_in[3];
  const float* bn0b = (const float*)d_in[4];
  const float* bn0m = (const float*)d_in[5];
  const float* bn0v = (const float*)d_in[6];
  const float* c1w  = (const float*)d_in[7];
  const float* c1b  = (const float*)d_in[8];
  const float* bn1g = (const float*)d_in[9];
  const float* bn1b = (const float*)d_in[10];
  const float* bn1m = (const float*)d_in[11];
  const float* bn1v = (const float*)d_in[12];
  const float* c2w  = (const float*)d_in[13];
  const float* c2b  = (const float*)d_in[14];
  const float* bn2g = (const float*)d_in[15];
  const float* bn2b = (const float*)d_in[16];
  const float* bn2m = (const float*)d_in[17];
  const float* bn2v = (const float*)d_in[18];
  const float* g1w  = (const float*)d_in[19];
  const float* g1b  = (const float*)d_in[20];
  const float* g1aw = (const float*)d_in[21];
  const float* g1ab = (const float*)d_in[22];
  const float* g2w  = (const float*)d_in[23];
  const float* g2b  = (const float*)d_in[24];
  const float* g2aw = (const float*)d_in[25];
  const float* g2ab = (const float*)d_in[26];
  const float* fcw  = (const float*)d_in[27];
  const float* fcb  = (const float*)d_in[28];
  float* ws = (float*)d_ws;

  const size_t SLOT = (size_t)(NN + 1) * 512;   // 2,097,664 floats
  float* slot0 = ws;                 // conv_time out -> Suf
  float* slot1 = ws + SLOT;          // conv1 out -> Pre
  float* slot2 = ws + 2 * SLOT;      // conv2 out -> g1 -> g2
  float* slot3 = ws + 3 * SLOT;      // h1 -> h2
  float* sm    = ws + 4 * SLOT;      // smalls
  float* s1    = sm;                 // 4096
  float* s2    = sm + 4096;
  float* svals = sm + 8192;
  int*   sidx  = (int*)(sm + 12288);
  int*   tarr  = (int*)(sm + 16384);
  float* Aarr  = sm + 20480;
  float* Barr  = sm + 24576;
  float* wp    = sm + 28672;
  float* wm    = sm + 32768;
  float* preden = sm + 36864;        // 4097
  float* sufden = sm + 40968;        // 4097
  float* csP   = sm + 45072;         // 128*512
  float* csM   = csP + 65536;
  float* offP  = csM + 65536;
  float* offM  = offP + 65536;
  int*   rnk   = (int*)(offM + 65536);   // 4096
  float* pp    = offM + 65536 + 4096;    // 16384

  // ---- convs ----
  k_conv_time<<<BB * 128 * TT0 / 256, 256, 0, stream>>>(x, ctw, ctb, bn0g, bn0b, bn0m, bn0v, slot0);
  k_conv_pool2<128, 4096><<<BB * 4 * 32, 256, 0, stream>>>(
      slot0, c1w, c1b, bn1g, bn1b, bn1m, bn1v, slot1, 256);
  k_conv_pool2<256, 2048><<<BB * 8 * 16, 256, 0, stream>>>(
      slot1, c2w, c2b, bn2g, bn2b, bn2m, bn2v, slot2, 512);

  // ---- GAT1 ----
  k_gemm<512, true, 128><<<dim3(32, 8), 256, 0, stream>>>(slot2, g1w, g1b, slot3, NN, 512);
  k_rowdot<512><<<NN / 4, 256, 0, stream>>>(slot3, g1aw, s1, s2);
  hipMemsetAsync(rnk, 0, NN * sizeof(int), stream);
  k_rank<<<dim3(16, 4), 256, 0, stream>>>(s2, rnk);
  k_scatter<<<16, 256, 0, stream>>>(s2, rnk, svals, sidx);
  k_tw<<<NN / 256, 256, 0, stream>>>(s1, svals, g1ab, tarr, Aarr, Barr, wp, wm);
  k_scan_den<<<1, 256, 0, stream>>>(wp, wm, preden, sufden);
  k_chunksum<512><<<128, 256, 0, stream>>>(slot3, sidx, wp, wm, csP, csM);
  k_chunkoff<512><<<2, 256, 0, stream>>>(csP, csM, offP, offM);
  k_scanwrite<512><<<128, 256, 0, stream>>>(slot3, sidx, wp, wm, offP, offM, slot1, slot0);
  k_apply<512><<<NN, 256, 0, stream>>>(slot1, slot0, preden, sufden, tarr, Aarr, Barr, slot2);

  // ---- GAT2 ----
  k_gemm<512, false, 64><<<dim3(64, 4), 256, 0, stream>>>(slot2, g2w, g2b, slot3, NN, 256);
  k_rowdot<256><<<NN / 4, 256, 0, stream>>>(slot3, g2aw, s1, s2);
  hipMemsetAsync(rnk, 0, NN * sizeof(int), stream);
  k_rank<<<dim3(16, 4), 256, 0, stream>>>(s2, rnk);
  k_scatter<<<16, 256, 0, stream>>>(s2, rnk, svals, sidx);
  k_tw<<<NN / 256, 256, 0, stream>>>(s1, svals, g2ab, tarr, Aarr, Barr, wp, wm);
  k_scan_den<<<1, 256, 0, stream>>>(wp, wm, preden, sufden);
  k_chunksum<256><<<128, 256, 0, stream>>>(slot3, sidx, wp, wm, csP, csM);
  k_chunkoff<256><<<1, 256, 0, stream>>>(csP, csM, offP, offM);
  k_scanwrite<256><<<128, 256, 0, stream>>>(slot3, sidx, wp, wm, offP, offM, slot1, slot0);
  k_apply<256><<<NN, 256, 0, stream>>>(slot1, slot0, preden, sufden, tarr, Aarr, Barr, slot2);

  // ---- head ----
  k_pool<<<BB * 16, 256, 0, stream>>>(slot2, pp);
  k_head2<<<1, 256, 0, stream>>>(pp, fcw, fcb, (float*)d_out);
}